// Round 1
// baseline (794.201 us; speedup 1.0000x reference)
//
#include <hip/hip_runtime.h>
#include <hip/hip_bf16.h>
#include <math.h>
#include <stdint.h>

// ---------------------------------------------------------------------------
// HMQ MLP: fake-quant(int8) GEMM1 + bias + exact GELU -> fake-quant -> GEMM2
// Strategy: int8 MFMA (mfma_i32_16x16x64_i8) with exact int32 accumulation.
// m97-style 128x128 tile, BK=64 (64B LDS rows), global_load_lds width-16.
// ---------------------------------------------------------------------------

typedef int v4i __attribute__((ext_vector_type(4)));

#define QMAXF 127.0f

// ---------------- small helpers ----------------

__device__ __forceinline__ void load_lds16(const void* g, void* l) {
    // global -> LDS direct, 16 bytes/lane. LDS dest must be wave-uniform base
    // + lane*16 (we arrange addresses so this holds).
    __builtin_amdgcn_global_load_lds(
        (__attribute__((address_space(1))) void*)(g),
        (__attribute__((address_space(3))) void*)(l),
        16, 0, 0);
}

// ---------------- init: zero the scale slots ----------------
__global__ void init_slots(unsigned int* slots) {
    if (threadIdx.x < 8) slots[threadIdx.x] = 0u;
}

// ---------------- absmax reduction (fp32, float4 vectorized) ----------------
__global__ void absmax_kernel(const float4* __restrict__ t, int n4,
                              unsigned int* __restrict__ slot) {
    float m = 0.f;
    int stride = gridDim.x * blockDim.x;
    for (int i = blockIdx.x * blockDim.x + threadIdx.x; i < n4; i += stride) {
        float4 v = t[i];
        m = fmaxf(m, fmaxf(fmaxf(fabsf(v.x), fabsf(v.y)),
                           fmaxf(fabsf(v.z), fabsf(v.w))));
    }
#pragma unroll
    for (int off = 32; off > 0; off >>= 1)
        m = fmaxf(m, __shfl_xor(m, off));
    if ((threadIdx.x & 63) == 0)
        atomicMax(slot, __float_as_uint(m));  // all values >= 0: uint order == float order
}

// ---------------- quantize fp32 -> int8 (replicates jnp numerics) ----------
__global__ void quant_kernel(const float4* __restrict__ t, int n4,
                             const float* __restrict__ slot,
                             char4* __restrict__ q) {
    const float s = fmaxf(*slot, 1e-8f) / QMAXF;  // same fp32 ops as reference
    int stride = gridDim.x * blockDim.x;
    for (int i = blockIdx.x * blockDim.x + threadIdx.x; i < n4; i += stride) {
        float4 v = t[i];
        char4 c;
        c.x = (char)fminf(fmaxf(rintf(v.x / s), -127.f), 127.f);
        c.y = (char)fminf(fmaxf(rintf(v.y / s), -127.f), 127.f);
        c.z = (char)fminf(fmaxf(rintf(v.z / s), -127.f), 127.f);
        c.w = (char)fminf(fmaxf(rintf(v.w / s), -127.f), 127.f);
        q[i] = c;
    }
}

// ---------------- int8 GEMM: C[M,N] = A[M,K] . B[N,K]^T ----------------
// Epilogue variants.
#define EPI_G1_STORE_F32 0   // h = gelu(acc*s + b); store fp32 h; atomicMax |h|
#define EPI_G1_MAXONLY   1   // h = gelu(...); atomicMax |h| only (no store)
#define EPI_G1_QUANT     2   // h = gelu(...); q = quant(h, scale_h); store int8
#define EPI_G2_OUT       3   // out = acc*s + b; store fp32

template <int EPI>
__global__ __launch_bounds__(256) void gemm_i8_kernel(
    const int8_t* __restrict__ A, const int8_t* __restrict__ B,
    int M, int N, int K,
    const float* __restrict__ slotA, const float* __restrict__ slotB,
    const float* __restrict__ bias,
    float* __restrict__ h_out,            // EPI 0
    unsigned int* __restrict__ maxslot,   // EPI 0/1
    const float* __restrict__ hslot,      // EPI 2
    int8_t* __restrict__ q_out,           // EPI 2
    float* __restrict__ out)              // EPI 3
{
    __shared__ __align__(16) int8_t sA[128 * 64];
    __shared__ __align__(16) int8_t sB[128 * 64];
    __shared__ float red[4];

    const int tid  = threadIdx.x;
    const int lane = tid & 63;
    const int wv   = tid >> 6;     // wave 0..3
    const int wm   = wv & 1;       // wave row (0/1) -> 64-row half
    const int wn   = wv >> 1;      // wave col (0/1) -> 64-col half

    const int bm = blockIdx.y * 128;
    const int bn = blockIdx.x * 128;

    const float sAB = (fmaxf(*slotA, 1e-8f) / QMAXF) *
                      (fmaxf(*slotB, 1e-8f) / QMAXF);

    v4i acc[4][4];
#pragma unroll
    for (int i = 0; i < 4; i++)
#pragma unroll
        for (int j = 0; j < 4; j++) acc[i][j] = (v4i){0, 0, 0, 0};

    // Staging: wave wv stages rows [wv*32, wv*32+32) of A-tile and B-tile.
    // lane -> row = base + lane/4, 16B chunk = (lane&3)*16.  LDS row stride 64B,
    // so LDS dest = wave-uniform base + lane*16 (global_load_lds requirement).
    const int8_t* gA = A + (size_t)(bm + wv * 32 + (lane >> 2)) * K + (lane & 3) * 16;
    const int8_t* gB = B + (size_t)(bn + wv * 32 + (lane >> 2)) * K + (lane & 3) * 16;
    int8_t* lA0 = sA + (wv * 32) * 64 + lane * 16;
    int8_t* lA1 = sA + (wv * 32 + 16) * 64 + lane * 16;
    int8_t* lB0 = sB + (wv * 32) * 64 + lane * 16;
    int8_t* lB1 = sB + (wv * 32 + 16) * 64 + lane * 16;
    const size_t rowskip = (size_t)16 * K;

    const int kiters = K >> 6;
    for (int kt = 0; kt < kiters; kt++) {
        __syncthreads();  // previous compute done before overwrite
        load_lds16(gA,           lA0);
        load_lds16(gA + rowskip, lA1);
        load_lds16(gB,           lB0);
        load_lds16(gB + rowskip, lB1);
        gA += 64;
        gB += 64;
        __syncthreads();  // drains vmcnt(0): staging visible

        v4i af[4], bf[4];
#pragma unroll
        for (int mi = 0; mi < 4; mi++)
            af[mi] = *(const v4i*)(sA + (wm * 64 + mi * 16 + (lane & 15)) * 64 +
                                   (lane >> 4) * 16);
#pragma unroll
        for (int ni = 0; ni < 4; ni++)
            bf[ni] = *(const v4i*)(sB + (wn * 64 + ni * 16 + (lane & 15)) * 64 +
                                   (lane >> 4) * 16);
#pragma unroll
        for (int mi = 0; mi < 4; mi++)
#pragma unroll
            for (int ni = 0; ni < 4; ni++)
                acc[mi][ni] = __builtin_amdgcn_mfma_i32_16x16x64_i8(
                    af[mi], bf[ni], acc[mi][ni], 0, 0, 0);
    }

    // ---------------- epilogue ----------------
    float sc_q = 0.f;
    if constexpr (EPI == EPI_G1_QUANT) sc_q = fmaxf(*hslot, 1e-8f) / QMAXF;
    float lmax = 0.f;

#pragma unroll
    for (int mi = 0; mi < 4; mi++) {
        const int row = bm + wm * 64 + mi * 16 + (lane >> 4) * 4;
#pragma unroll
        for (int ni = 0; ni < 4; ni++) {
            const int col = bn + wn * 64 + ni * 16 + (lane & 15);
            const float bv = bias[col];
#pragma unroll
            for (int r = 0; r < 4; r++) {
                // C/D layout: col = lane&15, row_in_16 = (lane>>4)*4 + r
                float val = (float)acc[mi][ni][r] * sAB + bv;
                if constexpr (EPI == EPI_G2_OUT) {
                    out[(size_t)(row + r) * N + col] = val;
                } else {
                    float g = 0.5f * val *
                              (1.0f + erff(val * 0.70710678118654752440f));
                    if constexpr (EPI == EPI_G1_STORE_F32) {
                        h_out[(size_t)(row + r) * N + col] = g;
                        lmax = fmaxf(lmax, fabsf(g));
                    } else if constexpr (EPI == EPI_G1_MAXONLY) {
                        lmax = fmaxf(lmax, fabsf(g));
                    } else {  // EPI_G1_QUANT
                        float qv = fminf(fmaxf(rintf(g / sc_q), -127.f), 127.f);
                        q_out[(size_t)(row + r) * N + col] = (int8_t)qv;
                    }
                }
            }
        }
    }

    if constexpr (EPI == EPI_G1_STORE_F32 || EPI == EPI_G1_MAXONLY) {
#pragma unroll
        for (int off = 32; off > 0; off >>= 1)
            lmax = fmaxf(lmax, __shfl_xor(lmax, off));
        if (lane == 0) red[wv] = lmax;
        __syncthreads();
        if (tid == 0) {
            float m = fmaxf(fmaxf(red[0], red[1]), fmaxf(red[2], red[3]));
            atomicMax(maxslot, __float_as_uint(m));
        }
    }
}

// ---------------------------------------------------------------------------

extern "C" void kernel_launch(void* const* d_in, const int* in_sizes, int n_in,
                              void* d_out, int out_size, void* d_ws, size_t ws_size,
                              hipStream_t stream) {
    const float* x  = (const float*)d_in[0];  // (4,4096,1024)
    const float* w1 = (const float*)d_in[1];  // (4096,1024)
    const float* b1 = (const float*)d_in[2];  // (4096,)
    const float* w2 = (const float*)d_in[3];  // (1024,4096)
    const float* b2 = (const float*)d_in[4];  // (1024,)
    float* out = (float*)d_out;               // (4,4096,1024) fp32

    const int D = 1024, H = 4096;
    const int Mrows = 4 * 4096;  // 16384

    // ---- workspace layout (all offsets 256B-aligned) ----
    uintptr_t ws = (uintptr_t)d_ws;
    unsigned int* slots = (unsigned int*)ws;         // [0]=|x| [1]=|w1| [2]=|w2| [3]=|h|
    const float* slotf = (const float*)ws;
    int8_t* xq  = (int8_t*)(ws + 256);
    int8_t* w1q = xq + (size_t)Mrows * D;            // 16 MB
    int8_t* w2q = w1q + (size_t)H * D;               // +4 MB
    int8_t* hq  = w2q + (size_t)D * H;               // +4 MB
    float*  hbuf = (float*)(hq + (size_t)Mrows * H); // +64 MB; hbuf = 256 MB
    const size_t need_f32 =
        256 + (size_t)Mrows * D + (size_t)H * D + (size_t)D * H +
        (size_t)Mrows * H + (size_t)Mrows * H * sizeof(float);  // ~345 MB
    const bool use_store = ws_size >= need_f32;  // ws_size constant -> same path every call

    // ---- scales ----
    init_slots<<<dim3(1), dim3(64), 0, stream>>>(slots);
    absmax_kernel<<<dim3(1024), dim3(256), 0, stream>>>(
        (const float4*)x, Mrows * D / 4, slots + 0);
    absmax_kernel<<<dim3(256), dim3(256), 0, stream>>>(
        (const float4*)w1, H * D / 4, slots + 1);
    absmax_kernel<<<dim3(256), dim3(256), 0, stream>>>(
        (const float4*)w2, D * H / 4, slots + 2);

    // ---- quantize inputs ----
    quant_kernel<<<dim3(1024), dim3(256), 0, stream>>>(
        (const float4*)x, Mrows * D / 4, slotf + 0, (char4*)xq);
    quant_kernel<<<dim3(256), dim3(256), 0, stream>>>(
        (const float4*)w1, H * D / 4, slotf + 1, (char4*)w1q);
    quant_kernel<<<dim3(256), dim3(256), 0, stream>>>(
        (const float4*)w2, D * H / 4, slotf + 2, (char4*)w2q);

    // ---- GEMM1: (16384x1024)·(4096x1024)^T + b1, GELU ----
    dim3 g1(H / 128, Mrows / 128);  // (32,128)
    if (use_store) {
        gemm_i8_kernel<EPI_G1_STORE_F32><<<g1, dim3(256), 0, stream>>>(
            xq, w1q, Mrows, H, D, slotf + 0, slotf + 1, b1,
            hbuf, slots + 3, nullptr, nullptr, nullptr);
        quant_kernel<<<dim3(2048), dim3(256), 0, stream>>>(
            (const float4*)hbuf, Mrows * H / 4, slotf + 3, (char4*)hq);
    } else {
        // recompute path: pass 1 finds max|gelu(h)|, pass 2 quantizes
        gemm_i8_kernel<EPI_G1_MAXONLY><<<g1, dim3(256), 0, stream>>>(
            xq, w1q, Mrows, H, D, slotf + 0, slotf + 1, b1,
            nullptr, slots + 3, nullptr, nullptr, nullptr);
        gemm_i8_kernel<EPI_G1_QUANT><<<g1, dim3(256), 0, stream>>>(
            xq, w1q, Mrows, H, D, slotf + 0, slotf + 1, b1,
            nullptr, nullptr, slotf + 3, hq, nullptr);
    }

    // ---- GEMM2: (16384x4096)·(1024x4096)^T + b2 -> out ----
    dim3 g2(D / 128, Mrows / 128);  // (8,128)
    gemm_i8_kernel<EPI_G2_OUT><<<g2, dim3(256), 0, stream>>>(
        hq, w2q, Mrows, D, H, slotf + 3, slotf + 2, b2,
        nullptr, nullptr, nullptr, nullptr, out);
}

// Round 2
// 677.228 us; speedup vs baseline: 1.1727x; 1.1727x over previous
//
#include <hip/hip_runtime.h>
#include <hip/hip_bf16.h>
#include <math.h>
#include <stdint.h>

// ---------------------------------------------------------------------------
// HMQ MLP: fake-quant(int8) GEMM1 + bias + exact GELU -> fake-quant -> GEMM2
// int8 MFMA (mfma_i32_16x16x64_i8), exact int32 accumulation.
// R2: single-barrier double-buffered K-loop (prefetch next tile after the
// barrier so the compiler's vmcnt(0)-before-s_barrier drains loads that had a
// full compute phase in flight), and h stored once as tile-scaled int16 to
// kill the second GEMM1 pass (with recompute fallback if ws is small).
// ---------------------------------------------------------------------------

typedef int    v4i   __attribute__((ext_vector_type(4)));
typedef short  short8 __attribute__((ext_vector_type(8)));
typedef int8_t char8  __attribute__((ext_vector_type(8)));

#define QMAXF 127.0f

__device__ __forceinline__ void load_lds16(const void* g, void* l) {
    // global -> LDS direct, 16B/lane; HW dest = wave-uniform base + lane*16.
    __builtin_amdgcn_global_load_lds(
        (__attribute__((address_space(1))) void*)(g),
        (__attribute__((address_space(3))) void*)(l),
        16, 0, 0);
}

// ---------------- init: zero the scale slots ----------------
__global__ void init_slots(unsigned int* slots) {
    if (threadIdx.x < 8) slots[threadIdx.x] = 0u;
}

// ---------------- absmax reduction (fp32, float4) ----------------
__global__ void absmax_kernel(const float4* __restrict__ t, int n4,
                              unsigned int* __restrict__ slot) {
    float m = 0.f;
    int stride = gridDim.x * blockDim.x;
    for (int i = blockIdx.x * blockDim.x + threadIdx.x; i < n4; i += stride) {
        float4 v = t[i];
        m = fmaxf(m, fmaxf(fmaxf(fabsf(v.x), fabsf(v.y)),
                           fmaxf(fabsf(v.z), fabsf(v.w))));
    }
#pragma unroll
    for (int off = 32; off > 0; off >>= 1)
        m = fmaxf(m, __shfl_xor(m, off));
    if ((threadIdx.x & 63) == 0)
        atomicMax(slot, __float_as_uint(m));  // vals >= 0: uint order == float order
}

// ---------------- quantize fp32 -> int8 (jnp numerics) ----------
__global__ void quant_kernel(const float4* __restrict__ t, int n4,
                             const float* __restrict__ slot,
                             char4* __restrict__ q) {
    const float s = fmaxf(*slot, 1e-8f) / QMAXF;
    int stride = gridDim.x * blockDim.x;
    for (int i = blockIdx.x * blockDim.x + threadIdx.x; i < n4; i += stride) {
        float4 v = t[i];
        char4 c;
        c.x = (char)fminf(fmaxf(rintf(v.x / s), -127.f), 127.f);
        c.y = (char)fminf(fmaxf(rintf(v.y / s), -127.f), 127.f);
        c.z = (char)fminf(fmaxf(rintf(v.z / s), -127.f), 127.f);
        c.w = (char)fminf(fmaxf(rintf(v.w / s), -127.f), 127.f);
        q[i] = c;
    }
}

// ---------------- decode tile-scaled int16 h -> int8 hq ----------
// h16[r][c] encodes g = h16 * tilescale[tile]/32767; hq = rint(g/scale_h).
// Fold: hq = rint(h16 * (ts/(32767*scale_h))). Flip error <= 0.002 LSB.
__global__ void quant_h_kernel(const short8* __restrict__ h16,
                               const float* __restrict__ tilescale,
                               const float* __restrict__ hslot,
                               char8* __restrict__ q, int n8) {
    const float sh = fmaxf(*hslot, 1e-8f) / QMAXF;
    int stride = gridDim.x * blockDim.x;
    for (int i = blockIdx.x * blockDim.x + threadIdx.x; i < n8; i += stride) {
        int r  = i >> 9;            // cols8 = 4096/8 = 512
        int c8 = i & 511;
        int tile = (r >> 7) * 32 + (c8 >> 4);   // (r/128)*(4096/128) + c/128
        float f = tilescale[tile] / (32767.f * sh);
        short8 v = h16[i];
        char8 o;
#pragma unroll
        for (int j = 0; j < 8; j++)
            o[j] = (int8_t)fminf(fmaxf(rintf((float)v[j] * f), -127.f), 127.f);
        q[i] = o;
    }
}

// ---------------- int8 GEMM: C[M,N] = A[M,K] . B[N,K]^T ----------------
#define EPI_G1_STORE_I16 0   // g=gelu(..); tilemax; store int16; atomicMax
#define EPI_G1_MAXONLY   1   // g=gelu(..); atomicMax only (fallback pass 1)
#define EPI_G1_QUANT     2   // g=gelu(..); store int8 (fallback pass 2)
#define EPI_G2_OUT       3   // out = acc*s + b; store fp32

template <int EPI>
__global__ __launch_bounds__(256) void gemm_i8_kernel(
    const int8_t* __restrict__ A, const int8_t* __restrict__ B,
    int M, int N, int K,
    const float* __restrict__ slotA, const float* __restrict__ slotB,
    const float* __restrict__ bias,
    int16_t* __restrict__ h16_out,        // EPI 0
    float* __restrict__ tilescale,        // EPI 0
    unsigned int* __restrict__ maxslot,   // EPI 0/1
    const float* __restrict__ hslot,      // EPI 2
    int8_t* __restrict__ q_out,           // EPI 2
    float* __restrict__ out)              // EPI 3
{
    __shared__ __align__(16) int8_t smem[2][2][128 * 64];  // [buf][A/B]
    __shared__ float red[4];
    __shared__ float ts_sh;

    const int tid  = threadIdx.x;
    const int lane = tid & 63;
    const int wv   = tid >> 6;
    const int wm   = wv & 1;
    const int wn   = wv >> 1;

    const int bm = blockIdx.x * 128;   // M fast: co-resident blocks share B-tile
    const int bn = blockIdx.y * 128;

    const float sAB = (fmaxf(*slotA, 1e-8f) / QMAXF) *
                      (fmaxf(*slotB, 1e-8f) / QMAXF);

    v4i acc[4][4] = {};

    // staging map: lane -> row = wv*32 + lane/4, chunk = (lane&3)*16
    const int8_t* gA = A + (size_t)(bm + wv * 32 + (lane >> 2)) * K + (lane & 3) * 16;
    const int8_t* gB = B + (size_t)(bn + wv * 32 + (lane >> 2)) * K + (lane & 3) * 16;
    const size_t rowskip = (size_t)16 * K;
    const int ldsoff = wv * 32 * 64 + lane * 16;

    // prologue: fill buf 0
    load_lds16(gA,           &smem[0][0][ldsoff]);
    load_lds16(gA + rowskip, &smem[0][0][ldsoff + 1024]);
    load_lds16(gB,           &smem[0][1][ldsoff]);
    load_lds16(gB + rowskip, &smem[0][1][ldsoff + 1024]);
    gA += 64; gB += 64;

    const int kiters = K >> 6;
    for (int kt = 0; kt < kiters; kt++) {
        __syncthreads();   // vmcnt(0)+lgkmcnt(0) drain: buf[kt&1] ready,
                           // prior reads of buf[(kt+1)&1] complete
        if (kt + 1 < kiters) {
            const int nb = (kt + 1) & 1;
            load_lds16(gA,           &smem[nb][0][ldsoff]);
            load_lds16(gA + rowskip, &smem[nb][0][ldsoff + 1024]);
            load_lds16(gB,           &smem[nb][1][ldsoff]);
            load_lds16(gB + rowskip, &smem[nb][1][ldsoff + 1024]);
            gA += 64; gB += 64;
        }
        const int cb = kt & 1;
        v4i af[4], bf[4];
#pragma unroll
        for (int mi = 0; mi < 4; mi++)
            af[mi] = *(const v4i*)&smem[cb][0][(wm * 64 + mi * 16 + (lane & 15)) * 64 +
                                               (lane >> 4) * 16];
#pragma unroll
        for (int ni = 0; ni < 4; ni++)
            bf[ni] = *(const v4i*)&smem[cb][1][(wn * 64 + ni * 16 + (lane & 15)) * 64 +
                                               (lane >> 4) * 16];
#pragma unroll
        for (int mi = 0; mi < 4; mi++)
#pragma unroll
            for (int ni = 0; ni < 4; ni++)
                acc[mi][ni] = __builtin_amdgcn_mfma_i32_16x16x64_i8(
                    af[mi], bf[ni], acc[mi][ni], 0, 0, 0);
    }

    // ---------------- epilogue ----------------
    float sc_q = 0.f;
    if constexpr (EPI == EPI_G1_QUANT) sc_q = fmaxf(*hslot, 1e-8f) / QMAXF;
    float lmax = 0.f;

    // phase 1: dequant + bias (+ GELU); park result bits back into acc regs
#pragma unroll
    for (int mi = 0; mi < 4; mi++) {
#pragma unroll
        for (int ni = 0; ni < 4; ni++) {
            const int col = bn + wn * 64 + ni * 16 + (lane & 15);
            const float bv = bias[col];
#pragma unroll
            for (int r = 0; r < 4; r++) {
                float val = (float)acc[mi][ni][r] * sAB + bv;
                if constexpr (EPI == EPI_G2_OUT) {
                    acc[mi][ni][r] = __float_as_int(val);
                } else {
                    float g = 0.5f * val *
                              (1.0f + erff(val * 0.70710678118654752440f));
                    lmax = fmaxf(lmax, fabsf(g));
                    acc[mi][ni][r] = __float_as_int(g);
                }
            }
        }
    }

    float enc = 0.f;
    if constexpr (EPI == EPI_G1_STORE_I16) {
        // block-tile max reduction
#pragma unroll
        for (int off = 32; off > 0; off >>= 1)
            lmax = fmaxf(lmax, __shfl_xor(lmax, off));
        if (lane == 0) red[wv] = lmax;
        __syncthreads();
        if (tid == 0) {
            float m = fmaxf(fmaxf(red[0], red[1]), fmaxf(red[2], red[3]));
            tilescale[blockIdx.x * gridDim.y + blockIdx.y] = m;
            atomicMax(maxslot, __float_as_uint(m));
            ts_sh = m;
        }
        __syncthreads();
        enc = 32767.f / fmaxf(ts_sh, 1e-20f);
    } else if constexpr (EPI == EPI_G1_MAXONLY) {
#pragma unroll
        for (int off = 32; off > 0; off >>= 1)
            lmax = fmaxf(lmax, __shfl_xor(lmax, off));
        if (lane == 0) red[wv] = lmax;
        __syncthreads();
        if (tid == 0) {
            float m = fmaxf(fmaxf(red[0], red[1]), fmaxf(red[2], red[3]));
            atomicMax(maxslot, __float_as_uint(m));
        }
    }

    // phase 2: stores
    if constexpr (EPI != EPI_G1_MAXONLY) {
#pragma unroll
        for (int mi = 0; mi < 4; mi++) {
            const int row = bm + wm * 64 + mi * 16 + (lane >> 4) * 4;
#pragma unroll
            for (int ni = 0; ni < 4; ni++) {
                const int col = bn + wn * 64 + ni * 16 + (lane & 15);
#pragma unroll
                for (int r = 0; r < 4; r++) {
                    float g = __int_as_float(acc[mi][ni][r]);
                    if constexpr (EPI == EPI_G2_OUT) {
                        out[(size_t)(row + r) * N + col] = g;
                    } else if constexpr (EPI == EPI_G1_STORE_I16) {
                        h16_out[(size_t)(row + r) * N + col] =
                            (int16_t)rintf(g * enc);
                    } else {  // EPI_G1_QUANT
                        float qv = fminf(fmaxf(rintf(g / sc_q), -127.f), 127.f);
                        q_out[(size_t)(row + r) * N + col] = (int8_t)qv;
                    }
                }
            }
        }
    }
}

// ---------------------------------------------------------------------------

extern "C" void kernel_launch(void* const* d_in, const int* in_sizes, int n_in,
                              void* d_out, int out_size, void* d_ws, size_t ws_size,
                              hipStream_t stream) {
    const float* x  = (const float*)d_in[0];  // (4,4096,1024)
    const float* w1 = (const float*)d_in[1];  // (4096,1024)
    const float* b1 = (const float*)d_in[2];  // (4096,)
    const float* w2 = (const float*)d_in[3];  // (1024,4096)
    const float* b2 = (const float*)d_in[4];  // (1024,)
    float* out = (float*)d_out;               // (4,4096,1024) fp32

    const int D = 1024, H = 4096;
    const int Mrows = 4 * 4096;  // 16384

    // ---- workspace layout ----
    uintptr_t ws = (uintptr_t)d_ws;
    unsigned int* slots = (unsigned int*)ws;   // [0]=|x| [1]=|w1| [2]=|w2| [3]=|h|
    const float* slotf = (const float*)ws;
    float* tiles = (float*)(ws + 256);                 // 4096 tile scales (16 KB)
    int8_t* xq  = (int8_t*)(ws + 256 + 65536);
    int8_t* w1q = xq + (size_t)Mrows * D;              // +16 MB
    int8_t* w2q = w1q + (size_t)H * D;                 // +4 MB
    int8_t* hq  = w2q + (size_t)D * H;                 // +4 MB
    int16_t* h16 = (int16_t*)(hq + (size_t)Mrows * H); // +64 MB
    const size_t need_i16 =
        256 + 65536 + (size_t)Mrows * D + 2u * (size_t)H * D +
        (size_t)Mrows * H + (size_t)Mrows * H * sizeof(int16_t);  // ~216 MB
    const bool use_store = ws_size >= need_i16;  // constant per session

    // ---- scales ----
    init_slots<<<dim3(1), dim3(64), 0, stream>>>(slots);
    absmax_kernel<<<dim3(1024), dim3(256), 0, stream>>>(
        (const float4*)x, Mrows * D / 4, slots + 0);
    absmax_kernel<<<dim3(256), dim3(256), 0, stream>>>(
        (const float4*)w1, H * D / 4, slots + 1);
    absmax_kernel<<<dim3(256), dim3(256), 0, stream>>>(
        (const float4*)w2, D * H / 4, slots + 2);

    // ---- quantize inputs ----
    quant_kernel<<<dim3(1024), dim3(256), 0, stream>>>(
        (const float4*)x, Mrows * D / 4, slotf + 0, (char4*)xq);
    quant_kernel<<<dim3(256), dim3(256), 0, stream>>>(
        (const float4*)w1, H * D / 4, slotf + 1, (char4*)w1q);
    quant_kernel<<<dim3(256), dim3(256), 0, stream>>>(
        (const float4*)w2, D * H / 4, slotf + 2, (char4*)w2q);

    // ---- GEMM1: (16384x1024)·(4096x1024)^T + b1, GELU ----
    dim3 g1(Mrows / 128, H / 128);  // (128, 32), M fast
    if (use_store) {
        gemm_i8_kernel<EPI_G1_STORE_I16><<<g1, dim3(256), 0, stream>>>(
            xq, w1q, Mrows, H, D, slotf + 0, slotf + 1, b1,
            h16, tiles, slots + 3, nullptr, nullptr, nullptr);
        quant_h_kernel<<<dim3(2048), dim3(256), 0, stream>>>(
            (const short8*)h16, tiles, slotf + 3, (char8*)hq, Mrows * H / 8);
    } else {
        gemm_i8_kernel<EPI_G1_MAXONLY><<<g1, dim3(256), 0, stream>>>(
            xq, w1q, Mrows, H, D, slotf + 0, slotf + 1, b1,
            nullptr, nullptr, slots + 3, nullptr, nullptr, nullptr);
        gemm_i8_kernel<EPI_G1_QUANT><<<g1, dim3(256), 0, stream>>>(
            xq, w1q, Mrows, H, D, slotf + 0, slotf + 1, b1,
            nullptr, nullptr, nullptr, slotf + 3, hq, nullptr);
    }

    // ---- GEMM2: (16384x4096)·(1024x4096)^T + b2 -> out ----
    dim3 g2(Mrows / 128, D / 128);  // (128, 8), M fast
    gemm_i8_kernel<EPI_G2_OUT><<<g2, dim3(256), 0, stream>>>(
        hq, w2q, Mrows, D, H, slotf + 3, slotf + 2, b2,
        nullptr, nullptr, nullptr, nullptr, nullptr, out);
}

// Round 3
// 548.496 us; speedup vs baseline: 1.4480x; 1.2347x over previous
//
#include <hip/hip_runtime.h>
#include <hip/hip_bf16.h>
#include <math.h>
#include <stdint.h>

// ---------------------------------------------------------------------------
// HMQ MLP: fake-quant(int8) GEMM1 + bias + exact GELU -> fake-quant -> GEMM2
// int8 MFMA (mfma_i32_16x16x64_i8), exact int32 accumulation.
// R3: operands pre-staged by the quant pass into fragment-major 1KB blocks:
//   staged[(rb*(K/64)+kc)*1024 + chunk*256 + row15*16 + k15]
// so global_load_lds reads contiguous 1KB and LDS fragment reads are the
// conflict-free stride-16B pattern (R2 had 8-way bank conflicts from the
// 64B-row layout). __launch_bounds__(256,4) for 4 blocks/CU.
// ---------------------------------------------------------------------------

typedef int    v4i    __attribute__((ext_vector_type(4)));
typedef short  short8 __attribute__((ext_vector_type(8)));

#define QMAXF 127.0f

__device__ __forceinline__ void load_lds16(const void* g, void* l) {
    __builtin_amdgcn_global_load_lds(
        (__attribute__((address_space(1))) void*)(g),
        (__attribute__((address_space(3))) void*)(l),
        16, 0, 0);
}

// ---------------- init: zero the scale slots ----------------
__global__ void init_slots(unsigned int* slots) {
    if (threadIdx.x < 8) slots[threadIdx.x] = 0u;
}

// ---------------- absmax reduction (fp32, float4) ----------------
__global__ void absmax_kernel(const float4* __restrict__ t, int n4,
                              unsigned int* __restrict__ slot) {
    float m = 0.f;
    int stride = gridDim.x * blockDim.x;
    for (int i = blockIdx.x * blockDim.x + threadIdx.x; i < n4; i += stride) {
        float4 v = t[i];
        m = fmaxf(m, fmaxf(fmaxf(fabsf(v.x), fabsf(v.y)),
                           fmaxf(fabsf(v.z), fabsf(v.w))));
    }
#pragma unroll
    for (int off = 32; off > 0; off >>= 1)
        m = fmaxf(m, __shfl_xor(m, off));
    if ((threadIdx.x & 63) == 0)
        atomicMax(slot, __float_as_uint(m));  // vals >= 0: uint order == float order
}

// ---------------- quantize fp32 -> staged int8 ----------------
// One wave per 1KB block (rb, kc): lane L handles row15=L&15, chunk=L>>4.
// Reads 16 fp32 (4x float4, contiguous 64B); writes contiguous 16B at
// q + wb*1024 + L*16. jnp numerics: rint(v / s), clamp +-127.
__global__ void quant_stage_kernel(const float* __restrict__ x, int kshift,
                                   int nblocks, const float* __restrict__ slot,
                                   int8_t* __restrict__ q) {
    const float s = fmaxf(*slot, 1e-8f) / QMAXF;
    const int lane = threadIdx.x & 63;
    const int wave0 = (blockIdx.x * blockDim.x + threadIdx.x) >> 6;
    const int nwaves = (gridDim.x * blockDim.x) >> 6;
    const int nkb = 1 << kshift;  // K/64
    for (int wb = wave0; wb < nblocks; wb += nwaves) {
        const int rb = wb >> kshift;
        const int kc = wb & (nkb - 1);
        const int row = rb * 16 + (lane & 15);
        const int k0  = kc * 64 + (lane >> 4) * 16;
        const float4* src = (const float4*)(x + ((size_t)row << (kshift + 6)) + k0);
        int8_t tmp[16];
#pragma unroll
        for (int j = 0; j < 4; j++) {
            float4 v = src[j];
            tmp[j*4+0] = (int8_t)fminf(fmaxf(rintf(v.x / s), -127.f), 127.f);
            tmp[j*4+1] = (int8_t)fminf(fmaxf(rintf(v.y / s), -127.f), 127.f);
            tmp[j*4+2] = (int8_t)fminf(fmaxf(rintf(v.z / s), -127.f), 127.f);
            tmp[j*4+3] = (int8_t)fminf(fmaxf(rintf(v.w / s), -127.f), 127.f);
        }
        *(int4*)(q + (size_t)wb * 1024 + lane * 16) = *(const int4*)tmp;
    }
}

// ---------------- decode tile-scaled int16 h -> staged int8 hq ----------
// h16 row-major (16384 x 4096); hq staged (kshift=6). Same wave->1KB-block map.
__global__ void quant_h_stage_kernel(const int16_t* __restrict__ h16,
                                     const float* __restrict__ tilescale,
                                     const float* __restrict__ hslot,
                                     int8_t* __restrict__ q, int nblocks) {
    const float sh = fmaxf(*hslot, 1e-8f) / QMAXF;
    const int lane = threadIdx.x & 63;
    const int wave0 = (blockIdx.x * blockDim.x + threadIdx.x) >> 6;
    const int nwaves = (gridDim.x * blockDim.x) >> 6;
    for (int wb = wave0; wb < nblocks; wb += nwaves) {
        const int rb = wb >> 6;
        const int kc = wb & 63;
        const int row = rb * 16 + (lane & 15);
        const int k0  = kc * 64 + (lane >> 4) * 16;
        const int tile = (row >> 7) * 32 + (k0 >> 7);
        const float f = tilescale[tile] / (32767.f * sh);
        const short8* hp = (const short8*)(h16 + (size_t)row * 4096 + k0);
        short8 a = hp[0], b = hp[1];
        int8_t tmp[16];
#pragma unroll
        for (int j = 0; j < 8; j++)
            tmp[j] = (int8_t)fminf(fmaxf(rintf((float)a[j] * f), -127.f), 127.f);
#pragma unroll
        for (int j = 0; j < 8; j++)
            tmp[8+j] = (int8_t)fminf(fmaxf(rintf((float)b[j] * f), -127.f), 127.f);
        *(int4*)(q + (size_t)wb * 1024 + lane * 16) = *(const int4*)tmp;
    }
}

// ---------------- int8 GEMM on staged operands ----------------
// A staged (M/16 x K/64 x 1KB), B staged (N/16 x K/64 x 1KB). C[M,N] = A.B^T.
#define EPI_G1_STORE_I16 0   // g=gelu(..); tilemax; store int16 row-major
#define EPI_G1_MAXONLY   1   // g=gelu(..); atomicMax only (fallback)
#define EPI_G1_QUANT     2   // g=gelu(..); store staged int8 (fallback)
#define EPI_G2_OUT       3   // out = acc*s + b; store fp32 row-major

template <int EPI>
__global__ __launch_bounds__(256, 4) void gemm_i8_kernel(
    const int8_t* __restrict__ A, const int8_t* __restrict__ B,
    int N, int K,
    const float* __restrict__ slotA, const float* __restrict__ slotB,
    const float* __restrict__ bias,
    int16_t* __restrict__ h16_out,        // EPI 0
    float* __restrict__ tilescale,        // EPI 0
    unsigned int* __restrict__ maxslot,   // EPI 0/1
    const float* __restrict__ hslot,      // EPI 2
    int8_t* __restrict__ q_out,           // EPI 2
    float* __restrict__ out)              // EPI 3
{
    __shared__ __align__(16) int8_t smem[2][2][8192];  // [buf][A/B], 8 x 1KB blocks
    __shared__ float red[4];
    __shared__ float ts_sh;

    const int tid  = threadIdx.x;
    const int lane = tid & 63;
    const int wv   = tid >> 6;
    const int wm   = wv & 1;
    const int wn   = wv >> 1;

    const int bm = blockIdx.x * 128;   // M fast: co-resident blocks share B tiles
    const int bn = blockIdx.y * 128;
    const int nkb = K >> 6;

    const float sAB = (fmaxf(*slotA, 1e-8f) / QMAXF) *
                      (fmaxf(*slotB, 1e-8f) / QMAXF);

    v4i acc[4][4] = {};

    // wave wv stages rowblocks {2wv, 2wv+1} of both tiles; 1KB contiguous each.
    const size_t rbstride = (size_t)nkb * 1024;
    const int8_t* gA = A + (size_t)((bm >> 4) + wv * 2) * rbstride + lane * 16;
    const int8_t* gB = B + (size_t)((bn >> 4) + wv * 2) * rbstride + lane * 16;
    const int ldsoff = wv * 2048 + lane * 16;

    // prologue: fill buf 0
    load_lds16(gA,            &smem[0][0][ldsoff]);
    load_lds16(gA + rbstride, &smem[0][0][ldsoff + 1024]);
    load_lds16(gB,            &smem[0][1][ldsoff]);
    load_lds16(gB + rbstride, &smem[0][1][ldsoff + 1024]);
    gA += 1024; gB += 1024;

    for (int kt = 0; kt < nkb; kt++) {
        __syncthreads();   // drains prefetch issued one full compute phase ago
        if (kt + 1 < nkb) {
            const int nb = (kt + 1) & 1;
            load_lds16(gA,            &smem[nb][0][ldsoff]);
            load_lds16(gA + rbstride, &smem[nb][0][ldsoff + 1024]);
            load_lds16(gB,            &smem[nb][1][ldsoff]);
            load_lds16(gB + rbstride, &smem[nb][1][ldsoff + 1024]);
            gA += 1024; gB += 1024;
        }
        const int cb = kt & 1;
        // fragment reads: addr = blockbase + lane*16 -> conflict-free
        v4i af[4], bf[4];
#pragma unroll
        for (int mi = 0; mi < 4; mi++)
            af[mi] = *(const v4i*)&smem[cb][0][(wm * 4 + mi) * 1024 + lane * 16];
#pragma unroll
        for (int ni = 0; ni < 4; ni++)
            bf[ni] = *(const v4i*)&smem[cb][1][(wn * 4 + ni) * 1024 + lane * 16];
#pragma unroll
        for (int mi = 0; mi < 4; mi++)
#pragma unroll
            for (int ni = 0; ni < 4; ni++)
                acc[mi][ni] = __builtin_amdgcn_mfma_i32_16x16x64_i8(
                    af[mi], bf[ni], acc[mi][ni], 0, 0, 0);
    }

    // ---------------- epilogue ----------------
    float sc_q = 0.f;
    if constexpr (EPI == EPI_G1_QUANT) sc_q = fmaxf(*hslot, 1e-8f) / QMAXF;
    float lmax = 0.f;

    // phase 1: dequant + bias (+ GELU); park result bits back into acc regs
#pragma unroll
    for (int mi = 0; mi < 4; mi++) {
#pragma unroll
        for (int ni = 0; ni < 4; ni++) {
            const int col = bn + wn * 64 + ni * 16 + (lane & 15);
            const float bv = bias[col];
#pragma unroll
            for (int r = 0; r < 4; r++) {
                float val = (float)acc[mi][ni][r] * sAB + bv;
                if constexpr (EPI == EPI_G2_OUT) {
                    acc[mi][ni][r] = __float_as_int(val);
                } else {
                    float g = 0.5f * val *
                              (1.0f + erff(val * 0.70710678118654752440f));
                    lmax = fmaxf(lmax, fabsf(g));
                    acc[mi][ni][r] = __float_as_int(g);
                }
            }
        }
    }

    float enc = 0.f;
    if constexpr (EPI == EPI_G1_STORE_I16 || EPI == EPI_G1_MAXONLY) {
#pragma unroll
        for (int off = 32; off > 0; off >>= 1)
            lmax = fmaxf(lmax, __shfl_xor(lmax, off));
        if (lane == 0) red[wv] = lmax;
        __syncthreads();
        if (tid == 0) {
            float m = fmaxf(fmaxf(red[0], red[1]), fmaxf(red[2], red[3]));
            if constexpr (EPI == EPI_G1_STORE_I16) {
                tilescale[blockIdx.x * gridDim.y + blockIdx.y] = m;
                ts_sh = m;
            }
            atomicMax(maxslot, __float_as_uint(m));
        }
        __syncthreads();
        if constexpr (EPI == EPI_G1_STORE_I16)
            enc = 32767.f / fmaxf(ts_sh, 1e-20f);
    }

    // phase 2: stores
    if constexpr (EPI != EPI_G1_MAXONLY) {
#pragma unroll
        for (int mi = 0; mi < 4; mi++) {
            const int row0 = bm + wm * 64 + mi * 16 + (lane >> 4) * 4;
#pragma unroll
            for (int ni = 0; ni < 4; ni++) {
                const int col = bn + wn * 64 + ni * 16 + (lane & 15);
#pragma unroll
                for (int r = 0; r < 4; r++) {
                    const int row = row0 + r;
                    float g = __int_as_float(acc[mi][ni][r]);
                    if constexpr (EPI == EPI_G2_OUT) {
                        out[(size_t)row * N + col] = g;
                    } else if constexpr (EPI == EPI_G1_STORE_I16) {
                        h16_out[(size_t)row * N + col] = (int16_t)rintf(g * enc);
                    } else {  // EPI_G1_QUANT: staged int8 write
                        float qv = fminf(fmaxf(rintf(g / sc_q), -127.f), 127.f);
                        size_t off = ((size_t)(row >> 4) * (N >> 6) + (col >> 6)) * 1024
                                   + ((col >> 4) & 3) * 256 + (row & 15) * 16 + (col & 15);
                        q_out[off] = (int8_t)qv;
                    }
                }
            }
        }
    }
}

// ---------------------------------------------------------------------------

extern "C" void kernel_launch(void* const* d_in, const int* in_sizes, int n_in,
                              void* d_out, int out_size, void* d_ws, size_t ws_size,
                              hipStream_t stream) {
    const float* x  = (const float*)d_in[0];  // (4,4096,1024)
    const float* w1 = (const float*)d_in[1];  // (4096,1024)
    const float* b1 = (const float*)d_in[2];  // (4096,)
    const float* w2 = (const float*)d_in[3];  // (1024,4096)
    const float* b2 = (const float*)d_in[4];  // (1024,)
    float* out = (float*)d_out;               // (4,4096,1024) fp32

    const int D = 1024, H = 4096;
    const int Mrows = 4 * 4096;  // 16384

    // ---- workspace layout ----
    uintptr_t ws = (uintptr_t)d_ws;
    unsigned int* slots = (unsigned int*)ws;   // [0]=|x| [1]=|w1| [2]=|w2| [3]=|h|
    const float* slotf = (const float*)ws;
    float* tiles = (float*)(ws + 256);                 // 4096 tile scales
    int8_t* xq  = (int8_t*)(ws + 256 + 65536);         // staged 16 MB
    int8_t* w1q = xq + (size_t)Mrows * D;              // staged 4 MB
    int8_t* w2q = w1q + (size_t)H * D;                 // staged 4 MB
    int8_t* hq  = w2q + (size_t)D * H;                 // staged 64 MB
    int16_t* h16 = (int16_t*)(hq + (size_t)Mrows * H); // row-major 128 MB
    const size_t need_i16 =
        256 + 65536 + (size_t)Mrows * D + 2u * (size_t)H * D +
        (size_t)Mrows * H + (size_t)Mrows * H * sizeof(int16_t);  // ~216 MB
    const bool use_store = ws_size >= need_i16;  // constant per session

    // ---- scales ----
    init_slots<<<dim3(1), dim3(64), 0, stream>>>(slots);
    absmax_kernel<<<dim3(1024), dim3(256), 0, stream>>>(
        (const float4*)x, Mrows * D / 4, slots + 0);
    absmax_kernel<<<dim3(256), dim3(256), 0, stream>>>(
        (const float4*)w1, H * D / 4, slots + 1);
    absmax_kernel<<<dim3(256), dim3(256), 0, stream>>>(
        (const float4*)w2, D * H / 4, slots + 2);

    // ---- quantize + stage inputs ----
    quant_stage_kernel<<<dim3(1024), dim3(256), 0, stream>>>(
        x, 4, (Mrows / 16) * (D / 64), slotf + 0, xq);   // 16384 blocks
    quant_stage_kernel<<<dim3(256), dim3(256), 0, stream>>>(
        w1, 4, (H / 16) * (D / 64), slotf + 1, w1q);     // 4096 blocks
    quant_stage_kernel<<<dim3(256), dim3(256), 0, stream>>>(
        w2, 6, (D / 16) * (H / 64), slotf + 2, w2q);     // 4096 blocks

    // ---- GEMM1: (16384x1024)·(4096x1024)^T + b1, GELU ----
    dim3 g1(Mrows / 128, H / 128);  // (128, 32), M fast
    if (use_store) {
        gemm_i8_kernel<EPI_G1_STORE_I16><<<g1, dim3(256), 0, stream>>>(
            xq, w1q, H, D, slotf + 0, slotf + 1, b1,
            h16, tiles, slots + 3, nullptr, nullptr, nullptr);
        quant_h_stage_kernel<<<dim3(2048), dim3(256), 0, stream>>>(
            h16, tiles, slotf + 3, hq, (Mrows / 16) * (H / 64));  // 65536 blocks
    } else {
        gemm_i8_kernel<EPI_G1_MAXONLY><<<g1, dim3(256), 0, stream>>>(
            xq, w1q, H, D, slotf + 0, slotf + 1, b1,
            nullptr, nullptr, slots + 3, nullptr, nullptr, nullptr);
        gemm_i8_kernel<EPI_G1_QUANT><<<g1, dim3(256), 0, stream>>>(
            xq, w1q, H, D, slotf + 0, slotf + 1, b1,
            nullptr, nullptr, nullptr, slotf + 3, hq, nullptr);
    }

    // ---- GEMM2: (16384x4096)·(1024x4096)^T + b2 -> out ----
    dim3 g2(Mrows / 128, D / 128);  // (128, 8), M fast
    gemm_i8_kernel<EPI_G2_OUT><<<g2, dim3(256), 0, stream>>>(
        hq, w2q, D, H, slotf + 3, slotf + 2, b2,
        nullptr, nullptr, nullptr, nullptr, nullptr, out);
}